// Round 6
// baseline (289.131 us; speedup 1.0000x reference)
//
#include <hip/hip_runtime.h>
#include <hip/hip_bf16.h>
#include <stdint.h>

#define B 8
#define N 4096
#define C 1024
#define H 16
#define D 64
// SCALE = D^-0.5 = 0.125 (folded into w_f at staging — exact pow2 scale)

static __device__ __forceinline__ float bf_lo(uint32_t u) {
    union { uint32_t i; float f; } c; c.i = u << 16; return c.f;
}
static __device__ __forceinline__ float bf_hi(uint32_t u) {
    union { uint32_t i; float f; } c; c.i = u & 0xffff0000u; return c.f;
}

// Kernel A: one wave per W row r (0..2C); computes k[b,*,r] (r<C) or v (r>=C)
// for ALL 8 batches -> W read exactly once. emb (32 KB) stays L2-hot.
__global__ __launch_bounds__(256, 2)
void kv_kernel(const float* __restrict__ emb,
               const float* __restrict__ Wk,
               const float* __restrict__ Wv,
               float* __restrict__ kbuf,
               float* __restrict__ vbuf) {
    int wave = (blockIdx.x * blockDim.x + threadIdx.x) >> 6;  // 0..2047
    int lane = threadIdx.x & 63;
    int r = wave;
    const float* Wrow = (r < C) ? (Wk + (size_t)r * C) : (Wv + (size_t)(r - C) * C);
    float4 w4[4];
#pragma unroll
    for (int j = 0; j < 4; ++j) w4[j] = *(const float4*)(Wrow + (lane + 64 * j) * 4);
    float acc[B];
#pragma unroll
    for (int b = 0; b < B; ++b) {
        const float* e = emb + (size_t)b * C;
        float a = 0.f;
#pragma unroll
        for (int j = 0; j < 4; ++j) {
            float4 e4 = *(const float4*)(e + (lane + 64 * j) * 4);
            a += w4[j].x * e4.x + w4[j].y * e4.y + w4[j].z * e4.z + w4[j].w * e4.w;
        }
        acc[b] = a;
    }
#pragma unroll
    for (int off = 32; off; off >>= 1)
#pragma unroll
        for (int b = 0; b < B; ++b) acc[b] += __shfl_xor(acc[b], off, 64);
    if (lane == 0) {
        float* dst = (r < C) ? (kbuf + r) : (vbuf + (r - C));
#pragma unroll
        for (int b = 0; b < B; ++b) dst[b * C] = acc[b];
    }
}

// Kernel B: fold weights with the BATCH LOOP INNERMOST so each Wq/Wp element
// is read exactly ONCE (8 MB total) and feeds 8 FMAs. 128 blocks x 256 thr.
__global__ __launch_bounds__(256)
void wu_kernel(const float* __restrict__ Wq,
               const float* __restrict__ Wp,
               const float* __restrict__ kbuf,
               const float* __restrict__ vbuf,
               __hip_bfloat16* __restrict__ wbuf,
               __hip_bfloat16* __restrict__ ubuf) {
    int id = blockIdx.x;
    int t = threadIdx.x;
    if (id < 64) {
        int h = id >> 2;
        int c = ((id & 3) << 8) + t;
        const float* kk = kbuf + h * D;  // k[b][hD+d] at kk[b*C + d]
        float acc[B];
#pragma unroll
        for (int b = 0; b < B; ++b) acc[b] = 0.f;
#pragma unroll 4
        for (int d = 0; d < D; ++d) {
            float wv = Wq[(size_t)(h * D + d) * C + c];
#pragma unroll
            for (int b = 0; b < B; ++b) acc[b] += kk[(size_t)b * C + d] * wv;
        }
#pragma unroll
        for (int b = 0; b < B; ++b)
            wbuf[(size_t)(b * H + h) * C + c] = __float2bfloat16(acc[b]);
    } else {
        int id2 = id - 64;
        int h = id2 >> 2;
        int cp = ((id2 & 3) << 8) + t;
        const float* vv = vbuf + h * D;  // v[b][hD+d] at vv[b*C + d]
        float aq[4][B];
#pragma unroll
        for (int q = 0; q < 4; ++q)
#pragma unroll
            for (int b = 0; b < B; ++b) aq[q][b] = 0.f;
#pragma unroll
        for (int q = 0; q < 4; ++q) {
#pragma unroll
            for (int m = 0; m < 4; ++m) {
                int d0 = q * 16 + m * 4;
                float4 w4 = *(const float4*)(Wp + (size_t)cp * C + h * D + d0);
#pragma unroll
                for (int b = 0; b < B; ++b) {
                    const float* vb = vv + (size_t)b * C + d0;
                    aq[q][b] += w4.x * vb[0] + w4.y * vb[1]
                              + w4.z * vb[2] + w4.w * vb[3];
                }
            }
        }
#pragma unroll
        for (int b = 0; b < B; ++b)
            ubuf[(size_t)(b * H + h) * C + cp] =
                __float2bfloat16((aq[0][b] + aq[1][b]) + (aq[2][b] + aq[3][b]));
    }
}

// Kernel C: fused main pass — f32-LDS *AND* 16 waves/CU.
// R5 post-mortem: VALU-issue bound (60% busy); ~25% of VALU was bf16 unpack.
// R4/R5 showed the false tradeoff {f32 weights XOR occupancy}; resolved by
// ONE 1024-thread block per CU: 128 KB static LDS (R4 proved this works),
// 16 waves/CU = 4/SIMD, zero unpack in the hot loop.
//   - SCALE folded into w_f at staging (exact 2^-3 scale -> bit-identical).
//   - Dot uses 4 independent 4-FMA chains per row + tree combine (ILP;
//     f32 rounding noise only).
//   - Head loop ROLLED (R3: code size caused a 9x stall).
//   - 2-row groups amortize each weight sweep; all reg arrays statically
//     indexed; ~110 VGPR (__launch_bounds__(1024,4) pins budget at 128).
// grid (N/128, B) = 256 blocks = exactly 1 per CU.
__global__ __launch_bounds__(1024, 4)
void main_kernel(const float* __restrict__ fea,
                 const __hip_bfloat16* __restrict__ wbuf,
                 const __hip_bfloat16* __restrict__ ubuf,
                 const float* __restrict__ bp,
                 float* __restrict__ out) {
    __shared__ float w_f[H * C];  // 64 KB, pre-scaled by 0.125
    __shared__ float u_f[H * C];  // 64 KB
    const int b = blockIdx.y;
    const int tile = blockIdx.x;
    const int tid = threadIdx.x;

    {
        const uint32_t* wsrc = (const uint32_t*)(wbuf + (size_t)b * H * C);
        const uint32_t* usrc = (const uint32_t*)(ubuf + (size_t)b * H * C);
#pragma unroll
        for (int i = 0; i < H * C / 2 / 1024; ++i) {  // 8 iters
            int wi = tid + i * 1024;
            uint32_t pw = wsrc[wi];
            uint32_t pu = usrc[wi];
            *(float2*)(w_f + 2 * wi) =
                make_float2(0.125f * bf_lo(pw), 0.125f * bf_hi(pw));
            *(float2*)(u_f + 2 * wi) = make_float2(bf_lo(pu), bf_hi(pu));
        }
    }
    __syncthreads();

    const int lane = tid & 63;
    const int wv = tid >> 6;          // 0..15
    const int row0 = tile * 128 + wv * 8;

    float4 bp4[4];
#pragma unroll
    for (int j = 0; j < 4; ++j) bp4[j] = *(const float4*)(bp + 4 * lane + 256 * j);

    const float* fbase = fea + ((size_t)b * N + row0) * C + 4 * lane;
    float* obase = out + ((size_t)b * N + row0) * C + 4 * lane;

#pragma unroll 1
    for (int g = 0; g < 4; ++g) {
        // Load 2 rows' fea slices (8 x dwordx4).
        float4 f[2][4];
#pragma unroll
        for (int r = 0; r < 2; ++r)
#pragma unroll
            for (int j = 0; j < 4; ++j)
                f[r][j] = *(const float4*)(fbase + (size_t)(2 * g + r) * C + 256 * j);

        float4 acc[2][4];
#pragma unroll
        for (int r = 0; r < 2; ++r)
#pragma unroll
            for (int j = 0; j < 4; ++j) {
                acc[r][j].x = f[r][j].x + bp4[j].x;
                acc[r][j].y = f[r][j].y + bp4[j].y;
                acc[r][j].z = f[r][j].z + bp4[j].z;
                acc[r][j].w = f[r][j].w + bp4[j].w;
            }

#pragma unroll 1
        for (int h = 0; h < H; ++h) {
            const float* wrow = w_f + h * C + 4 * lane;
            // 4 independent partials per row (ILP), tree-combined.
            float sp[2][4];
#pragma unroll
            for (int j = 0; j < 4; ++j) {
                float4 w4 = *(const float4*)(wrow + 256 * j);
#pragma unroll
                for (int r = 0; r < 2; ++r)
                    sp[r][j] = f[r][j].x * w4.x + f[r][j].y * w4.y
                             + f[r][j].z * w4.z + f[r][j].w * w4.w;
            }
            float s[2];
#pragma unroll
            for (int r = 0; r < 2; ++r)
                s[r] = (sp[r][0] + sp[r][1]) + (sp[r][2] + sp[r][3]);
#pragma unroll
            for (int off = 32; off; off >>= 1)
#pragma unroll
                for (int r = 0; r < 2; ++r) s[r] += __shfl_xor(s[r], off, 64);
#pragma unroll
            for (int r = 0; r < 2; ++r)
                s[r] = 1.f / (1.f + __expf(-s[r]));  // scale pre-folded into w_f

            const float* urow = u_f + h * C + 4 * lane;
#pragma unroll
            for (int j = 0; j < 4; ++j) {
                float4 u4 = *(const float4*)(urow + 256 * j);
#pragma unroll
                for (int r = 0; r < 2; ++r) {
                    acc[r][j].x += s[r] * u4.x; acc[r][j].y += s[r] * u4.y;
                    acc[r][j].z += s[r] * u4.z; acc[r][j].w += s[r] * u4.w;
                }
            }
        }

#pragma unroll
        for (int r = 0; r < 2; ++r)
#pragma unroll
            for (int j = 0; j < 4; ++j)
                *(float4*)(obase + (size_t)(2 * g + r) * C + 256 * j) = acc[r][j];
    }
}

extern "C" void kernel_launch(void* const* d_in, const int* in_sizes, int n_in,
                              void* d_out, int out_size, void* d_ws, size_t ws_size,
                              hipStream_t stream) {
    const float* fea = (const float*)d_in[0];
    const float* emb = (const float*)d_in[1];
    const float* Wq  = (const float*)d_in[2];
    const float* Wk  = (const float*)d_in[3];
    const float* Wv  = (const float*)d_in[4];
    const float* Wp  = (const float*)d_in[5];
    const float* bp  = (const float*)d_in[6];
    float* out = (float*)d_out;

    char* ws = (char*)d_ws;
    float* kbuf = (float*)ws;                                  // B*C f32 = 32KB
    float* vbuf = (float*)(ws + 32 * 1024);                    // 32KB
    __hip_bfloat16* wbuf = (__hip_bfloat16*)(ws + 64 * 1024);  // B*H*C bf16 = 256KB
    __hip_bfloat16* ubuf = (__hip_bfloat16*)(ws + 320 * 1024); // 256KB

    hipLaunchKernelGGL(kv_kernel, dim3(2 * C / 4), dim3(256), 0, stream,
                       emb, Wk, Wv, kbuf, vbuf);
    hipLaunchKernelGGL(wu_kernel, dim3(128), dim3(256), 0, stream,
                       Wq, Wp, kbuf, vbuf, wbuf, ubuf);
    hipLaunchKernelGGL(main_kernel, dim3(N / 128, B), dim3(1024), 0, stream,
                       fea, wbuf, ubuf, bp, out);
}

// Round 7
// 280.792 us; speedup vs baseline: 1.0297x; 1.0297x over previous
//
#include <hip/hip_runtime.h>
#include <hip/hip_bf16.h>
#include <stdint.h>

#define B 8
#define N 4096
#define C 1024
#define H 16
#define D 64
// SCALE = D^-0.5 = 0.125 (folded into w_f at staging — exact pow2 scale)

static __device__ __forceinline__ float bf_lo(uint32_t u) {
    union { uint32_t i; float f; } c; c.i = u << 16; return c.f;
}
static __device__ __forceinline__ float bf_hi(uint32_t u) {
    union { uint32_t i; float f; } c; c.i = u & 0xffff0000u; return c.f;
}

// VALU-only wave64 sum: row_shr prefix + row_bcast combine; total in lane 63.
// (standard GCN/CDNA cross-lane sequence; update_dpp(old=0,...,bound_ctrl=1)
// makes invalid/masked lanes contribute 0.)
#define DPP_ADD(s, ctrl, rmask)                                              \
    s += __int_as_float(__builtin_amdgcn_update_dpp(                         \
        0, __float_as_int(s), ctrl, rmask, 0xf, true))

static __device__ __forceinline__ float wave_sum_dpp(float s) {
    DPP_ADD(s, 0x111, 0xf);  // row_shr:1
    DPP_ADD(s, 0x112, 0xf);  // row_shr:2
    DPP_ADD(s, 0x114, 0xf);  // row_shr:4
    DPP_ADD(s, 0x118, 0xf);  // row_shr:8  -> lane15 of each row = row sum
    DPP_ADD(s, 0x142, 0xa);  // row_bcast:15 -> rows 1,3 add prev row sum
    DPP_ADD(s, 0x143, 0xc);  // row_bcast:31 -> rows 2,3 add lanes0-31 sum
    return s;                // lane 63 holds the full 64-lane sum
}

// Kernel A: one wave per W row r (0..2C); computes k[b,*,r] (r<C) or v (r>=C)
// for ALL 8 batches -> W read exactly once. emb (32 KB) stays L2-hot.
__global__ __launch_bounds__(256, 2)
void kv_kernel(const float* __restrict__ emb,
               const float* __restrict__ Wk,
               const float* __restrict__ Wv,
               float* __restrict__ kbuf,
               float* __restrict__ vbuf) {
    int wave = (blockIdx.x * blockDim.x + threadIdx.x) >> 6;  // 0..2047
    int lane = threadIdx.x & 63;
    int r = wave;
    const float* Wrow = (r < C) ? (Wk + (size_t)r * C) : (Wv + (size_t)(r - C) * C);
    float4 w4[4];
#pragma unroll
    for (int j = 0; j < 4; ++j) w4[j] = *(const float4*)(Wrow + (lane + 64 * j) * 4);
    float acc[B];
#pragma unroll
    for (int b = 0; b < B; ++b) {
        const float* e = emb + (size_t)b * C;
        float a = 0.f;
#pragma unroll
        for (int j = 0; j < 4; ++j) {
            float4 e4 = *(const float4*)(e + (lane + 64 * j) * 4);
            a += w4[j].x * e4.x + w4[j].y * e4.y + w4[j].z * e4.z + w4[j].w * e4.w;
        }
        acc[b] = a;
    }
#pragma unroll
    for (int off = 32; off; off >>= 1)
#pragma unroll
        for (int b = 0; b < B; ++b) acc[b] += __shfl_xor(acc[b], off, 64);
    if (lane == 0) {
        float* dst = (r < C) ? (kbuf + r) : (vbuf + (r - C));
#pragma unroll
        for (int b = 0; b < B; ++b) dst[b * C] = acc[b];
    }
}

// Kernel B: fold weights with the BATCH LOOP INNERMOST so each Wq/Wp element
// is read exactly ONCE (8 MB total) and feeds 8 FMAs. 128 blocks x 256 thr.
__global__ __launch_bounds__(256)
void wu_kernel(const float* __restrict__ Wq,
               const float* __restrict__ Wp,
               const float* __restrict__ kbuf,
               const float* __restrict__ vbuf,
               __hip_bfloat16* __restrict__ wbuf,
               __hip_bfloat16* __restrict__ ubuf) {
    int id = blockIdx.x;
    int t = threadIdx.x;
    if (id < 64) {
        int h = id >> 2;
        int c = ((id & 3) << 8) + t;
        const float* kk = kbuf + h * D;  // k[b][hD+d] at kk[b*C + d]
        float acc[B];
#pragma unroll
        for (int b = 0; b < B; ++b) acc[b] = 0.f;
#pragma unroll 4
        for (int d = 0; d < D; ++d) {
            float wv = Wq[(size_t)(h * D + d) * C + c];
#pragma unroll
            for (int b = 0; b < B; ++b) acc[b] += kk[(size_t)b * C + d] * wv;
        }
#pragma unroll
        for (int b = 0; b < B; ++b)
            wbuf[(size_t)(b * H + h) * C + c] = __float2bfloat16(acc[b]);
    } else {
        int id2 = id - 64;
        int h = id2 >> 2;
        int cp = ((id2 & 3) << 8) + t;
        const float* vv = vbuf + h * D;  // v[b][hD+d] at vv[b*C + d]
        float aq[4][B];
#pragma unroll
        for (int q = 0; q < 4; ++q)
#pragma unroll
            for (int b = 0; b < B; ++b) aq[q][b] = 0.f;
#pragma unroll
        for (int q = 0; q < 4; ++q) {
#pragma unroll
            for (int m = 0; m < 4; ++m) {
                int d0 = q * 16 + m * 4;
                float4 w4 = *(const float4*)(Wp + (size_t)cp * C + h * D + d0);
#pragma unroll
                for (int b = 0; b < B; ++b) {
                    const float* vb = vv + (size_t)b * C + d0;
                    aq[q][b] += w4.x * vb[0] + w4.y * vb[1]
                              + w4.z * vb[2] + w4.w * vb[3];
                }
            }
        }
#pragma unroll
        for (int b = 0; b < B; ++b)
            ubuf[(size_t)(b * H + h) * C + cp] =
                __float2bfloat16((aq[0][b] + aq[1][b]) + (aq[2][b] + aq[3][b]));
    }
}

// Kernel C: fused main pass — 4-rows-per-sweep, two-phase, DPP reduction.
// R6 post-mortem: LDS pipe ~70% busy (41 us b128 reads + 31 us shuffle
// swizzles) was the bottleneck; VALU only 42%.
//   - 4-row groups halve weight-read traffic per row (vs 2-row).
//   - Register wall broken by TWO PHASES per group: phase 1 (logits) uses
//     f[4][4]; wave-uniform sigmoids parked in 64-float/wave LDS scratch;
//     phase 2 REUSES f as acc (f dead after logits) and sweeps u with
//     broadcast sig reads. Peak live ~110 VGPR -> fits 128 (4 waves/SIMD).
//   - Butterfly -> DPP row_shr/row_bcast sum (VALU pipe) + one shfl(.,63):
//     LDS swizzles per wave drop 768 -> 128.
// Kept from prior rounds: rolled head loops (R3: code size), f32 weights +
// folded SCALE (R6), 1024-thr block = 1 block/CU, 0-conflict LDS patterns.
// LDS = 132 KB (<160). Reduction order changes (DPP prefix vs butterfly):
// f32-level noise only; absmax remains bf16-dominated.
__global__ __launch_bounds__(1024, 4)
void main_kernel(const float* __restrict__ fea,
                 const __hip_bfloat16* __restrict__ wbuf,
                 const __hip_bfloat16* __restrict__ ubuf,
                 const float* __restrict__ bp,
                 float* __restrict__ out) {
    __shared__ float w_f[H * C];       // 64 KB, pre-scaled by 0.125
    __shared__ float u_f[H * C];       // 64 KB
    __shared__ float sig_s[16 * 64];   // 4 KB: per-wave 16 heads x 4 rows
    const int b = blockIdx.y;
    const int tile = blockIdx.x;
    const int tid = threadIdx.x;

    {
        const uint32_t* wsrc = (const uint32_t*)(wbuf + (size_t)b * H * C);
        const uint32_t* usrc = (const uint32_t*)(ubuf + (size_t)b * H * C);
#pragma unroll
        for (int i = 0; i < H * C / 2 / 1024; ++i) {  // 8 iters
            int wi = tid + i * 1024;
            uint32_t pw = wsrc[wi];
            uint32_t pu = usrc[wi];
            *(float2*)(w_f + 2 * wi) =
                make_float2(0.125f * bf_lo(pw), 0.125f * bf_hi(pw));
            *(float2*)(u_f + 2 * wi) = make_float2(bf_lo(pu), bf_hi(pu));
        }
    }
    __syncthreads();

    const int lane = tid & 63;
    const int wv = tid >> 6;          // 0..15
    const int row0 = tile * 128 + wv * 8;
    float* sigp = sig_s + wv * 64;

    float4 bp4[4];
#pragma unroll
    for (int j = 0; j < 4; ++j) bp4[j] = *(const float4*)(bp + 4 * lane + 256 * j);

    const float* fbase = fea + ((size_t)b * N + row0) * C + 4 * lane;
    float* obase = out + ((size_t)b * N + row0) * C + 4 * lane;

#pragma unroll 1
    for (int g = 0; g < 2; ++g) {
        // ---- Phase 1: logits for 4 rows x 16 heads ----
        float4 f[4][4];
#pragma unroll
        for (int r = 0; r < 4; ++r)
#pragma unroll
            for (int j = 0; j < 4; ++j)
                f[r][j] = *(const float4*)(fbase + (size_t)(4 * g + r) * C + 256 * j);

#pragma unroll 1
        for (int h = 0; h < H; ++h) {
            const float* wrow = w_f + h * C + 4 * lane;
            float4 w4[4];
#pragma unroll
            for (int j = 0; j < 4; ++j) w4[j] = *(const float4*)(wrow + 256 * j);
            float s[4];
#pragma unroll
            for (int r = 0; r < 4; ++r) {
                float a = f[r][0].x * w4[0].x + f[r][0].y * w4[0].y
                        + f[r][0].z * w4[0].z + f[r][0].w * w4[0].w;
                float c2 = f[r][1].x * w4[1].x + f[r][1].y * w4[1].y
                         + f[r][1].z * w4[1].z + f[r][1].w * w4[1].w;
                float d2 = f[r][2].x * w4[2].x + f[r][2].y * w4[2].y
                         + f[r][2].z * w4[2].z + f[r][2].w * w4[2].w;
                float e2 = f[r][3].x * w4[3].x + f[r][3].y * w4[3].y
                         + f[r][3].z * w4[3].z + f[r][3].w * w4[3].w;
                s[r] = (a + c2) + (d2 + e2);
            }
#pragma unroll
            for (int r = 0; r < 4; ++r) s[r] = wave_sum_dpp(s[r]);
#pragma unroll
            for (int r = 0; r < 4; ++r) s[r] = __shfl(s[r], 63, 64);
#pragma unroll
            for (int r = 0; r < 4; ++r) s[r] = 1.f / (1.f + __expf(-s[r]));
            if (lane == 0)
                *(float4*)(sigp + h * 4) = make_float4(s[0], s[1], s[2], s[3]);
        }

        // ---- Phase 2: f becomes acc; sweep u with broadcast sig ----
#pragma unroll
        for (int r = 0; r < 4; ++r)
#pragma unroll
            for (int j = 0; j < 4; ++j) {
                f[r][j].x += bp4[j].x; f[r][j].y += bp4[j].y;
                f[r][j].z += bp4[j].z; f[r][j].w += bp4[j].w;
            }

#pragma unroll 1
        for (int h = 0; h < H; ++h) {
            float4 sg = *(const float4*)(sigp + h * 4);  // uniform broadcast
            float sgr[4] = {sg.x, sg.y, sg.z, sg.w};
            const float* urow = u_f + h * C + 4 * lane;
#pragma unroll
            for (int j = 0; j < 4; ++j) {
                float4 u4 = *(const float4*)(urow + 256 * j);
#pragma unroll
                for (int r = 0; r < 4; ++r) {
                    f[r][j].x += sgr[r] * u4.x; f[r][j].y += sgr[r] * u4.y;
                    f[r][j].z += sgr[r] * u4.z; f[r][j].w += sgr[r] * u4.w;
                }
            }
        }

#pragma unroll
        for (int r = 0; r < 4; ++r)
#pragma unroll
            for (int j = 0; j < 4; ++j)
                *(float4*)(obase + (size_t)(4 * g + r) * C + 256 * j) = f[r][j];
    }
}

extern "C" void kernel_launch(void* const* d_in, const int* in_sizes, int n_in,
                              void* d_out, int out_size, void* d_ws, size_t ws_size,
                              hipStream_t stream) {
    const float* fea = (const float*)d_in[0];
    const float* emb = (const float*)d_in[1];
    const float* Wq  = (const float*)d_in[2];
    const float* Wk  = (const float*)d_in[3];
    const float* Wv  = (const float*)d_in[4];
    const float* Wp  = (const float*)d_in[5];
    const float* bp  = (const float*)d_in[6];
    float* out = (float*)d_out;

    char* ws = (char*)d_ws;
    float* kbuf = (float*)ws;                                  // B*C f32 = 32KB
    float* vbuf = (float*)(ws + 32 * 1024);                    // 32KB
    __hip_bfloat16* wbuf = (__hip_bfloat16*)(ws + 64 * 1024);  // B*H*C bf16 = 256KB
    __hip_bfloat16* ubuf = (__hip_bfloat16*)(ws + 320 * 1024); // 256KB

    hipLaunchKernelGGL(kv_kernel, dim3(2 * C / 4), dim3(256), 0, stream,
                       emb, Wk, Wv, kbuf, vbuf);
    hipLaunchKernelGGL(wu_kernel, dim3(128), dim3(256), 0, stream,
                       Wq, Wp, kbuf, vbuf, wbuf, ubuf);
    hipLaunchKernelGGL(main_kernel, dim3(N / 128, B), dim3(1024), 0, stream,
                       fea, wbuf, ubuf, bp, out);
}